// Round 8
// baseline (218.599 us; speedup 1.0000x reference)
//
#include <hip/hip_runtime.h>
#include <hip/hip_bf16.h>

#define B_ 4
#define S_ 4096
#define D_ 1024
#define H_ 128

typedef unsigned short u16;
typedef unsigned int u32;
typedef short s16x8 __attribute__((ext_vector_type(8)));   // 8 bf16 (4 VGPRs)
typedef float f32x4 __attribute__((ext_vector_type(4)));   // MFMA 16x16 acc
typedef float f32x16 __attribute__((ext_vector_type(16))); // MFMA 32x32 acc

__device__ __forceinline__ u16 f2bf(float f) {
    u32 x = __float_as_uint(f);
    u32 r = x + 0x7fffu + ((x >> 16) & 1u);   // RNE
    return (u16)(r >> 16);
}

// v_cvt_pk_bf16_f32: dst = {bf16(a) lo16, bf16(b) hi16}
__device__ __forceinline__ u32 cvtpk_bf16(float a, float b) {
    u32 r;
    asm("v_cvt_pk_bf16_f32 %0, %1, %2" : "=v"(r) : "v"(a), "v"(b));
    return r;
}
// v_permlane32_swap_b32: exchanges x.hi-lanes <-> y.lo-lanes (both updated)
__device__ __forceinline__ void pl32swap(u32& x, u32& y) {
    asm("v_permlane32_swap_b32 %0, %1" : "+v"(x), "+v"(y));
}

// async global->LDS, 16 B per lane (m97 pattern; zero staging VGPRs)
__device__ __forceinline__ void gl_lds16(const u16* g, u16* l) {
    __builtin_amdgcn_global_load_lds(
        (const __attribute__((address_space(1))) u32*)g,
        (__attribute__((address_space(3))) u32*)l, 16, 0, 0);
}

// ---------------------------------------------------------------------------
// Kernel 0: input dtype detection (fp32 vs bf16). Verified in round 3.
// ---------------------------------------------------------------------------
__global__ void detect_dtype_kernel(const u32* __restrict__ w, int* __restrict__ flag) {
    __shared__ int smax[256];
    const int tid = threadIdx.x;
    int m = 0;
    for (int i = tid; i < 1024; i += 256) {
        u32 x = w[i];
        m = max(m, max((int)((x >> 7) & 0xFF), (int)((x >> 23) & 0xFF)));
    }
    smax[tid] = m;
    __syncthreads();
    if (tid == 0) {
        int mm = 0;
        for (int i = 0; i < 256; ++i) mm = max(mm, smax[i]);
        *flag = (mm >= 200) ? 1 : 0;
    }
}

// ---------------------------------------------------------------------------
// Kernel 0b: W -> Wt, bf16, transposed + tiled so a B-fragment is 16 B
// contiguous: Wt[((mat*32+kt)*128 + n)*32 + k]. Tile (mat,kt) = 8 KB.
// ---------------------------------------------------------------------------
__global__ __launch_bounds__(256) void prep_w_kernel(
    const void* __restrict__ Wq, const void* __restrict__ Wk, const void* __restrict__ Wv,
    u16* __restrict__ Wt, const int* __restrict__ dflag)
{
    const int kt = blockIdx.x, mat = blockIdx.y;
    const void* W = (mat == 0) ? Wq : (mat == 1) ? Wk : Wv;
    const int isf = *dflag;
    const int t = threadIdx.x;
    const int kk = t >> 3;            // 0..31 (k within tile)
    const int n0 = (t & 7) * 16;      // 16 n per thread
    u16 vals[16];
    if (isf) {
        const float* wp = (const float*)W + (size_t)(kt * 32 + kk) * H_ + n0;
#pragma unroll
        for (int i = 0; i < 16; ++i) vals[i] = f2bf(wp[i]);
    } else {
        const u16* wp = (const u16*)W + (size_t)(kt * 32 + kk) * H_ + n0;
#pragma unroll
        for (int i = 0; i < 16; ++i) vals[i] = wp[i];
    }
    const size_t base = (size_t)(mat * 32 + kt) * 128;
#pragma unroll
    for (int i = 0; i < 16; ++i)
        Wt[(base + n0 + i) * 32 + kk] = vals[i];
}

// ---------------------------------------------------------------------------
// Kernel 1: fused QKV GEMM v4 (unchanged from measured-good round).
// ---------------------------------------------------------------------------
__global__ __launch_bounds__(256) void qkv_kernel(
    const void* __restrict__ Xv, const u16* __restrict__ Wt,
    u16* __restrict__ Qo, u16* __restrict__ Ko, u16* __restrict__ Vto,
    const int* __restrict__ dflag)
{
    __shared__ u16 Ws[2][384 * 32];                              // 2 x 24 KB
    __shared__ union { u16 qk[32 * 136]; u16 vt[128 * 40]; } OsU; // 10.2 KB

    const int isf = *dflag;
    const int tid = threadIdx.x;
    const int w = tid >> 6, lane = tid & 63;
    const int r = lane & 15, q = lane >> 4;
    const size_t m0 = (size_t)blockIdx.x * 32;

    f32x4 acc[2][6];   // [row strip][frag]
#pragma unroll
    for (int s2 = 0; s2 < 2; ++s2)
#pragma unroll
        for (int i = 0; i < 6; ++i) acc[s2][i] = (f32x4){0.f, 0.f, 0.f, 0.f};

    const float* xf0 = (const float*)Xv + (m0 + r) * D_;
    const float* xf1 = (const float*)Xv + (m0 + 16 + r) * D_;
    const u16*   xb0 = (const u16*)Xv + (m0 + r) * D_;
    const u16*   xb1 = (const u16*)Xv + (m0 + 16 + r) * D_;

    float4 af[2][2];   // fp32 A prefetch (2 strips x 8 floats)
    uint4  ab[2];      // bf16 A prefetch

    // ---- async-stage W tile kt=0 into Ws[0] ----
#pragma unroll
    for (int i = 0; i < 6; ++i) {
        int c = tid + i * 256;      // 1536 chunks of 16 B; mat = c>>9
        gl_lds16(Wt + (size_t)((c >> 9) * 32) * 4096 + (c & 511) * 8, &Ws[0][c * 8]);
    }
    // ---- A prefetch kt=0 ----
    if (isf) {
        af[0][0] = *(const float4*)(xf0 + q * 8);
        af[0][1] = *(const float4*)(xf0 + q * 8 + 4);
        af[1][0] = *(const float4*)(xf1 + q * 8);
        af[1][1] = *(const float4*)(xf1 + q * 8 + 4);
    } else {
        ab[0] = *(const uint4*)(xb0 + q * 8);
        ab[1] = *(const uint4*)(xb1 + q * 8);
    }

    for (int kt = 0; kt < 32; ++kt) {
        const int buf = kt & 1;
        __syncthreads();   // drains vmcnt: Ws[buf] + A(kt) ready; readers of Ws[buf^1] done

        if (kt + 1 < 32) {  // async-stage W tile kt+1 into the other buffer
#pragma unroll
            for (int i = 0; i < 6; ++i) {
                int c = tid + i * 256;
                gl_lds16(Wt + (size_t)((c >> 9) * 32 + kt + 1) * 4096 + (c & 511) * 8,
                         &Ws[buf ^ 1][c * 8]);
            }
        }

        // convert A regs (loaded last iteration) to bf16 frags
        s16x8 a[2];
        if (isf) {
#pragma unroll
            for (int s2 = 0; s2 < 2; ++s2) {
                union { u16 u[8]; s16x8 v; } pk;
                pk.u[0] = f2bf(af[s2][0].x); pk.u[1] = f2bf(af[s2][0].y);
                pk.u[2] = f2bf(af[s2][0].z); pk.u[3] = f2bf(af[s2][0].w);
                pk.u[4] = f2bf(af[s2][1].x); pk.u[5] = f2bf(af[s2][1].y);
                pk.u[6] = f2bf(af[s2][1].z); pk.u[7] = f2bf(af[s2][1].w);
                a[s2] = pk.v;
            }
        } else {
            a[0] = *(const s16x8*)&ab[0];
            a[1] = *(const s16x8*)&ab[1];
        }

        if (kt + 1 < 32) {   // A prefetch next kt (in flight during MFMAs)
            const int k0 = (kt + 1) * 32;
            if (isf) {
                af[0][0] = *(const float4*)(xf0 + k0 + q * 8);
                af[0][1] = *(const float4*)(xf0 + k0 + q * 8 + 4);
                af[1][0] = *(const float4*)(xf1 + k0 + q * 8);
                af[1][1] = *(const float4*)(xf1 + k0 + q * 8 + 4);
            } else {
                ab[0] = *(const uint4*)(xb0 + k0 + q * 8);
                ab[1] = *(const uint4*)(xb1 + k0 + q * 8);
            }
        }

#pragma unroll
        for (int i = 0; i < 6; ++i) {
            int c = w * 6 + i;   // mat = c>>3, nt = c&7
            s16x8 b = *(const s16x8*)&Ws[buf][(c >> 3) * 4096 + ((c & 7) * 16 + r) * 32 + q * 8];
            acc[0][i] = __builtin_amdgcn_mfma_f32_16x16x32_bf16(a[0], b, acc[0][i], 0, 0, 0);
            acc[1][i] = __builtin_amdgcn_mfma_f32_16x16x32_bf16(a[1], b, acc[1][i], 0, 0, 0);
        }
    }

    // ---- epilogue: Q and K row-major via LDS bounce ----
    u16* outs[2] = {Qo, Ko};
    for (int m = 0; m < 2; ++m) {
        const float sc = (m == 0) ? 0.08838834764831845f : 1.0f;
        __syncthreads();
#pragma unroll
        for (int i = 0; i < 6; ++i) {
            int c = w * 6 + i;
            if ((c >> 3) == m) {
                int nt = c & 7;
#pragma unroll
                for (int s2 = 0; s2 < 2; ++s2)
#pragma unroll
                    for (int reg = 0; reg < 4; ++reg)
                        OsU.qk[(s2 * 16 + q * 4 + reg) * 136 + nt * 16 + r] = f2bf(acc[s2][i][reg] * sc);
            }
        }
        __syncthreads();
        u16* Out = outs[m];
#pragma unroll
        for (int it = 0; it < 2; ++it) {
            int c = tid + it * 256;
            int row = c >> 4, col = (c & 15) * 8;
            *(uint4*)(Out + (m0 + row) * H_ + col) = *(const uint4*)&OsU.qk[row * 136 + col];
        }
    }

    // ---- V transposed: OsU.vt[h][s_local], then Vt[b][h][s] global ----
    __syncthreads();
#pragma unroll
    for (int i = 0; i < 6; ++i) {
        int c = w * 6 + i;
        if ((c >> 3) == 2) {
            int nt = c & 7;
#pragma unroll
            for (int s2 = 0; s2 < 2; ++s2)
#pragma unroll
                for (int reg = 0; reg < 4; ++reg)
                    OsU.vt[(nt * 16 + r) * 40 + s2 * 16 + q * 4 + reg] = f2bf(acc[s2][i][reg]);
        }
    }
    __syncthreads();
    {
        const int bb = blockIdx.x >> 7;           // 128 blocks per batch
        const int s0 = (blockIdx.x & 127) * 32;
        // 128 h-rows x 32 s = 512 uint4 chunks: h = c>>2, sh = (c&3)*8
#pragma unroll
        for (int it = 0; it < 2; ++it) {
            int c = tid + it * 256;
            int h = c >> 2, sh = (c & 3) * 8;
            *(uint4*)(Vto + ((size_t)bb * H_ + h) * S_ + s0 + sh) =
                *(const uint4*)&OsU.vt[h * 40 + sh];
        }
    }
}

// ---------------------------------------------------------------------------
// Kernel 2: causal flash attention — swapped-QK^T in-register softmax,
// 8 waves, 8-way key split, SMALL-LDS epilogue. Round-7 post-mortem: the
// 64-66KB combine buffer silently capped residency at ~1 block/CU every
// round since r5 (runtime won't co-schedule two 64KB-class blocks), so the
// TLP hypothesis was never actually tested. This version keeps the k-loop
// BYTE-IDENTICAL to r7 and shrinks the epilogue to opS[32][128] (16 KB)
// with SERIALIZED wave accumulation (8 cheap barriers, once per block).
// VGPR ~100 (<=128 -> 4 waves/SIMD), LDS ~17.4 KB (2 blocks = 35 KB) ->
// 2 blocks/CU = 16 waves/CU = 50% occupancy ceiling, grid-limited exactly.
// Pairing grid: bid and bid+256 (qt, 127-qt) co-land -> constant work/CU.
// ---------------------------------------------------------------------------
__global__ __launch_bounds__(512) void attn_kernel(
    const u16* __restrict__ Q, const u16* __restrict__ K, const u16* __restrict__ Vt,
    void* __restrict__ out, const int* __restrict__ dflag)
{
    __shared__ float opS[32][128];      // single combine buffer (16 KB)
    __shared__ float lpS[8][32];        // per-wave l partials

    const int isf = *dflag;
    const int tid = threadIdx.x;
    const int w = tid >> 6, lane = tid & 63;
    const int l31 = lane & 31, hi = lane >> 5;
    const int bid = blockIdx.x;
    const int b = bid & 3;
    const int qt = (bid < 256) ? (bid >> 2) : (127 - ((bid - 256) >> 2));

    const u16* Qg  = Q  + ((size_t)b * S_ + (size_t)qt * 32) * H_;
    const u16* Kg  = K  + (size_t)b * S_ * H_;
    const u16* Vtg = Vt + (size_t)b * H_ * S_;

    // Q as B-operand frags: lane -> qrow = l31, k(h) = sl*16 + hi*8 + [0..8)
    s16x8 qf[8];
#pragma unroll
    for (int sl = 0; sl < 8; ++sl)
        qf[sl] = *(const s16x8*)(Qg + (size_t)l31 * H_ + sl * 16 + hi * 8);

    f32x16 accO[4];
#pragma unroll
    for (int hg = 0; hg < 4; ++hg)
#pragma unroll
        for (int i = 0; i < 16; ++i) accO[hg][i] = 0.f;
    float lp = 0.f;

    // K as A-operand frags for first chunk: lane -> key = l31, k(h) likewise
    s16x8 kf[8];
    if (w <= qt) {
#pragma unroll
        for (int sl = 0; sl < 8; ++sl)
            kf[sl] = *(const s16x8*)(Kg + ((size_t)w * 32 + l31) * H_ + sl * 16 + hi * 8);
    }

    for (int c = w; c <= qt; c += 8) {
        const int kb = c * 32;

        // V as B-operand frags: lane -> h = hg*32+l31, k(key) = ks*16 + hi*8 + [0..8)
        s16x8 vf[4][2];
#pragma unroll
        for (int hg = 0; hg < 4; ++hg)
#pragma unroll
            for (int ks = 0; ks < 2; ++ks)
                vf[hg][ks] = *(const s16x8*)(Vtg + (size_t)(hg * 32 + l31) * S_ + kb + ks * 16 + hi * 8);

        // ---- S^T = K Q^T : lane holds qrow = l31, key(r,hi) = (r&3)+8*(r>>2)+4*hi ----
        f32x16 sacc;
#pragma unroll
        for (int i = 0; i < 16; ++i) sacc[i] = 0.f;
#pragma unroll
        for (int sl = 0; sl < 8; ++sl)
            sacc = __builtin_amdgcn_mfma_f32_32x32x16_bf16(kf[sl], qf[sl], sacc, 0, 0, 0);

        // ---- prefetch K frags for this wave's next chunk (covered by softmax+PV) ----
        if (c + 8 <= qt) {
#pragma unroll
            for (int sl = 0; sl < 8; ++sl)
                kf[sl] = *(const s16x8*)(Kg + ((size_t)(kb + 256) + l31) * H_ + sl * 16 + hi * 8);
        }

        // ---- lane-local softmax (no max-pass; clamp 80), mask own diagonal chunk ----
        const bool diag = (c == qt);
        float p[16];
#pragma unroll
        for (int r = 0; r < 16; ++r) {
            float s = fminf(sacc[r], 80.f);
            float pv = __expf(s);
            if (diag && ((r & 3) + 8 * (r >> 2) + 4 * hi) > l31) pv = 0.f;
            lp += pv;
            p[r] = pv;
        }

        // ---- P -> PV A-frags: 8 cvt_pk + 4 permlane32_swap (T12 recipe) ----
        u32 w01 = cvtpk_bf16(p[0], p[1]),  w23 = cvtpk_bf16(p[2], p[3]);
        u32 w45 = cvtpk_bf16(p[4], p[5]),  w67 = cvtpk_bf16(p[6], p[7]);
        pl32swap(w01, w45);
        pl32swap(w23, w67);
        u32 x01 = cvtpk_bf16(p[8], p[9]),  x23 = cvtpk_bf16(p[10], p[11]);
        u32 x45 = cvtpk_bf16(p[12], p[13]), x67 = cvtpk_bf16(p[14], p[15]);
        pl32swap(x01, x45);
        pl32swap(x23, x67);
        union { u32 u[4]; s16x8 v; } pa0, pa1;
        pa0.u[0] = w01; pa0.u[1] = w23; pa0.u[2] = w45; pa0.u[3] = w67;
        pa1.u[0] = x01; pa1.u[1] = x23; pa1.u[2] = x45; pa1.u[3] = x67;

        // ---- O += P V : D lane holds h = hg*32+l31, qrow(r,hi) ----
#pragma unroll
        for (int hg = 0; hg < 4; ++hg) {
            accO[hg] = __builtin_amdgcn_mfma_f32_32x32x16_bf16(pa0.v, vf[hg][0], accO[hg], 0, 0, 0);
            accO[hg] = __builtin_amdgcn_mfma_f32_32x32x16_bf16(pa1.v, vf[hg][1], accO[hg], 0, 0, 0);
        }
    }

    // ---- combine the two key-halves of l (lane pair L, L+32) ----
    lp += __shfl_xor(lp, 32);
    if (lane < 32) lpS[w][l31] = lp;

    // ---- serialized combine through the small buffer: wave s writes/adds ----
    for (int s = 0; s < 8; ++s) {
        if (w == s) {
            if (s == 0) {
#pragma unroll
                for (int hg = 0; hg < 4; ++hg)
#pragma unroll
                    for (int r = 0; r < 16; ++r)
                        opS[(r & 3) + 8 * (r >> 2) + 4 * hi][hg * 32 + l31] = accO[hg][r];
            } else {
#pragma unroll
                for (int hg = 0; hg < 4; ++hg)
#pragma unroll
                    for (int r = 0; r < 16; ++r)
                        opS[(r & 3) + 8 * (r >> 2) + 4 * hi][hg * 32 + l31] += accO[hg][r];
            }
        }
        __syncthreads();
    }

    // ---- final: normalize, store (512 threads) ----
    {
        const int qrow = tid >> 4;           // 0..31
        const int hs = (tid & 15) * 8;       // 0..120
        float l = 0.f;
#pragma unroll
        for (int s = 0; s < 8; ++s) l += lpS[s][qrow];
        const float inv = 1.0f / l;
        float vals[8];
#pragma unroll
        for (int i = 0; i < 8; i += 4) {
            float4 a0 = *(const float4*)&opS[qrow][hs + i];
            vals[i + 0] = a0.x * inv;
            vals[i + 1] = a0.y * inv;
            vals[i + 2] = a0.z * inv;
            vals[i + 3] = a0.w * inv;
        }
        const size_t orow = (size_t)b * S_ + (size_t)qt * 32 + qrow;
        if (isf) {
            float* dst = (float*)out + orow * H_ + hs;
            *(float4*)(dst) = *(const float4*)(&vals[0]);
            *(float4*)(dst + 4) = *(const float4*)(&vals[4]);
        } else {
            u16* dst = (u16*)out + orow * H_ + hs;
            union { u16 u[8]; uint4 v; } pk;
#pragma unroll
            for (int i = 0; i < 8; ++i) pk.u[i] = f2bf(vals[i]);
            *(uint4*)dst = pk.v;
        }
    }
}

extern "C" void kernel_launch(void* const* d_in, const int* in_sizes, int n_in,
                              void* d_out, int out_size, void* d_ws, size_t ws_size,
                              hipStream_t stream) {
    (void)in_sizes; (void)n_in; (void)out_size; (void)ws_size;
    const void* X  = d_in[0];
    const void* Wq = d_in[1];
    const void* Wk = d_in[2];
    const void* Wv = d_in[3];

    int* dflag = (int*)d_ws;                          // 256 B header
    u16* Qw = (u16*)((char*)d_ws + 256);
    const size_t n = (size_t)B_ * S_ * H_;            // 2M elems per tensor
    u16* Kw = Qw + n;
    u16* Vtw = Kw + n;                                // V stored transposed [b][h][s]
    u16* Wt = Vtw + n;                                // 3*1024*128 bf16 = 768 KB

    detect_dtype_kernel<<<1, 256, 0, stream>>>((const u32*)Wq, dflag);
    prep_w_kernel<<<dim3(32, 3), 256, 0, stream>>>(Wq, Wk, Wv, Wt, dflag);
    qkv_kernel<<<512, 256, 0, stream>>>(X, Wt, Qw, Kw, Vtw, dflag);
    attn_kernel<<<512, 512, 0, stream>>>(Qw, Kw, Vtw, d_out, dflag);
}

// Round 10
// 191.894 us; speedup vs baseline: 1.1392x; 1.1392x over previous
//
#include <hip/hip_runtime.h>
#include <hip/hip_bf16.h>

#define B_ 4
#define S_ 4096
#define D_ 1024
#define H_ 128

typedef unsigned short u16;
typedef unsigned int u32;
typedef short s16x8 __attribute__((ext_vector_type(8)));   // 8 bf16 (4 VGPRs)
typedef float f32x4 __attribute__((ext_vector_type(4)));   // MFMA 16x16 acc
typedef float f32x16 __attribute__((ext_vector_type(16))); // MFMA 32x32 acc

__device__ __forceinline__ u16 f2bf(float f) {
    u32 x = __float_as_uint(f);
    u32 r = x + 0x7fffu + ((x >> 16) & 1u);   // RNE
    return (u16)(r >> 16);
}

// v_cvt_pk_bf16_f32: dst = {bf16(a) lo16, bf16(b) hi16}
__device__ __forceinline__ u32 cvtpk_bf16(float a, float b) {
    u32 r;
    asm("v_cvt_pk_bf16_f32 %0, %1, %2" : "=v"(r) : "v"(a), "v"(b));
    return r;
}
// v_permlane32_swap_b32: exchanges x.hi-lanes <-> y.lo-lanes (both updated)
__device__ __forceinline__ void pl32swap(u32& x, u32& y) {
    asm("v_permlane32_swap_b32 %0, %1" : "+v"(x), "+v"(y));
}

// async global->LDS, 16 B per lane (m97 pattern; zero staging VGPRs).
// LDS dest must be wave-uniform base + lane*16 (m104) -- callers ensure.
__device__ __forceinline__ void gl_lds16(const u16* g, u16* l) {
    __builtin_amdgcn_global_load_lds(
        (const __attribute__((address_space(1))) u32*)g,
        (__attribute__((address_space(3))) u32*)l, 16, 0, 0);
}

// ---------------------------------------------------------------------------
// Kernel 0: input dtype detection (fp32 vs bf16). Verified in round 3.
// ---------------------------------------------------------------------------
__global__ void detect_dtype_kernel(const u32* __restrict__ w, int* __restrict__ flag) {
    __shared__ int smax[256];
    const int tid = threadIdx.x;
    int m = 0;
    for (int i = tid; i < 1024; i += 256) {
        u32 x = w[i];
        m = max(m, max((int)((x >> 7) & 0xFF), (int)((x >> 23) & 0xFF)));
    }
    smax[tid] = m;
    __syncthreads();
    if (tid == 0) {
        int mm = 0;
        for (int i = 0; i < 256; ++i) mm = max(mm, smax[i]);
        *flag = (mm >= 200) ? 1 : 0;
    }
}

// ---------------------------------------------------------------------------
// Kernel 0b: W -> Wt, bf16, transposed + tiled so a B-fragment is 16 B
// contiguous: Wt[((mat*32+kt)*128 + n)*32 + k]. Tile (mat,kt) = 8 KB.
// ---------------------------------------------------------------------------
__global__ __launch_bounds__(256) void prep_w_kernel(
    const void* __restrict__ Wq, const void* __restrict__ Wk, const void* __restrict__ Wv,
    u16* __restrict__ Wt, const int* __restrict__ dflag)
{
    const int kt = blockIdx.x, mat = blockIdx.y;
    const void* W = (mat == 0) ? Wq : (mat == 1) ? Wk : Wv;
    const int isf = *dflag;
    const int t = threadIdx.x;
    const int kk = t >> 3;            // 0..31 (k within tile)
    const int n0 = (t & 7) * 16;      // 16 n per thread
    u16 vals[16];
    if (isf) {
        const float* wp = (const float*)W + (size_t)(kt * 32 + kk) * H_ + n0;
#pragma unroll
        for (int i = 0; i < 16; ++i) vals[i] = f2bf(wp[i]);
    } else {
        const u16* wp = (const u16*)W + (size_t)(kt * 32 + kk) * H_ + n0;
#pragma unroll
        for (int i = 0; i < 16; ++i) vals[i] = wp[i];
    }
    const size_t base = (size_t)(mat * 32 + kt) * 128;
#pragma unroll
    for (int i = 0; i < 16; ++i)
        Wt[(base + n0 + i) * 32 + kk] = vals[i];
}

// ---------------------------------------------------------------------------
// Kernel 1: fused QKV GEMM v4 (unchanged from measured-good round).
// ---------------------------------------------------------------------------
__global__ __launch_bounds__(256) void qkv_kernel(
    const void* __restrict__ Xv, const u16* __restrict__ Wt,
    u16* __restrict__ Qo, u16* __restrict__ Ko, u16* __restrict__ Vto,
    const int* __restrict__ dflag)
{
    __shared__ u16 Ws[2][384 * 32];                              // 2 x 24 KB
    __shared__ union { u16 qk[32 * 136]; u16 vt[128 * 40]; } OsU; // 10.2 KB

    const int isf = *dflag;
    const int tid = threadIdx.x;
    const int w = tid >> 6, lane = tid & 63;
    const int r = lane & 15, q = lane >> 4;
    const size_t m0 = (size_t)blockIdx.x * 32;

    f32x4 acc[2][6];   // [row strip][frag]
#pragma unroll
    for (int s2 = 0; s2 < 2; ++s2)
#pragma unroll
        for (int i = 0; i < 6; ++i) acc[s2][i] = (f32x4){0.f, 0.f, 0.f, 0.f};

    const float* xf0 = (const float*)Xv + (m0 + r) * D_;
    const float* xf1 = (const float*)Xv + (m0 + 16 + r) * D_;
    const u16*   xb0 = (const u16*)Xv + (m0 + r) * D_;
    const u16*   xb1 = (const u16*)Xv + (m0 + 16 + r) * D_;

    float4 af[2][2];   // fp32 A prefetch (2 strips x 8 floats)
    uint4  ab[2];      // bf16 A prefetch

    // ---- async-stage W tile kt=0 into Ws[0] ----
#pragma unroll
    for (int i = 0; i < 6; ++i) {
        int c = tid + i * 256;      // 1536 chunks of 16 B; mat = c>>9
        gl_lds16(Wt + (size_t)((c >> 9) * 32) * 4096 + (c & 511) * 8, &Ws[0][c * 8]);
    }
    // ---- A prefetch kt=0 ----
    if (isf) {
        af[0][0] = *(const float4*)(xf0 + q * 8);
        af[0][1] = *(const float4*)(xf0 + q * 8 + 4);
        af[1][0] = *(const float4*)(xf1 + q * 8);
        af[1][1] = *(const float4*)(xf1 + q * 8 + 4);
    } else {
        ab[0] = *(const uint4*)(xb0 + q * 8);
        ab[1] = *(const uint4*)(xb1 + q * 8);
    }

    for (int kt = 0; kt < 32; ++kt) {
        const int buf = kt & 1;
        __syncthreads();   // drains vmcnt: Ws[buf] + A(kt) ready; readers of Ws[buf^1] done

        if (kt + 1 < 32) {  // async-stage W tile kt+1 into the other buffer
#pragma unroll
            for (int i = 0; i < 6; ++i) {
                int c = tid + i * 256;
                gl_lds16(Wt + (size_t)((c >> 9) * 32 + kt + 1) * 4096 + (c & 511) * 8,
                         &Ws[buf ^ 1][c * 8]);
            }
        }

        // convert A regs (loaded last iteration) to bf16 frags
        s16x8 a[2];
        if (isf) {
#pragma unroll
            for (int s2 = 0; s2 < 2; ++s2) {
                union { u16 u[8]; s16x8 v; } pk;
                pk.u[0] = f2bf(af[s2][0].x); pk.u[1] = f2bf(af[s2][0].y);
                pk.u[2] = f2bf(af[s2][0].z); pk.u[3] = f2bf(af[s2][0].w);
                pk.u[4] = f2bf(af[s2][1].x); pk.u[5] = f2bf(af[s2][1].y);
                pk.u[6] = f2bf(af[s2][1].z); pk.u[7] = f2bf(af[s2][1].w);
                a[s2] = pk.v;
            }
        } else {
            a[0] = *(const s16x8*)&ab[0];
            a[1] = *(const s16x8*)&ab[1];
        }

        if (kt + 1 < 32) {   // A prefetch next kt (in flight during MFMAs)
            const int k0 = (kt + 1) * 32;
            if (isf) {
                af[0][0] = *(const float4*)(xf0 + k0 + q * 8);
                af[0][1] = *(const float4*)(xf0 + k0 + q * 8 + 4);
                af[1][0] = *(const float4*)(xf1 + k0 + q * 8);
                af[1][1] = *(const float4*)(xf1 + k0 + q * 8 + 4);
            } else {
                ab[0] = *(const uint4*)(xb0 + k0 + q * 8);
                ab[1] = *(const uint4*)(xb1 + k0 + q * 8);
            }
        }

#pragma unroll
        for (int i = 0; i < 6; ++i) {
            int c = w * 6 + i;   // mat = c>>3, nt = c&7
            s16x8 b = *(const s16x8*)&Ws[buf][(c >> 3) * 4096 + ((c & 7) * 16 + r) * 32 + q * 8];
            acc[0][i] = __builtin_amdgcn_mfma_f32_16x16x32_bf16(a[0], b, acc[0][i], 0, 0, 0);
            acc[1][i] = __builtin_amdgcn_mfma_f32_16x16x32_bf16(a[1], b, acc[1][i], 0, 0, 0);
        }
    }

    // ---- epilogue: Q and K row-major via LDS bounce ----
    u16* outs[2] = {Qo, Ko};
    for (int m = 0; m < 2; ++m) {
        const float sc = (m == 0) ? 0.08838834764831845f : 1.0f;
        __syncthreads();
#pragma unroll
        for (int i = 0; i < 6; ++i) {
            int c = w * 6 + i;
            if ((c >> 3) == m) {
                int nt = c & 7;
#pragma unroll
                for (int s2 = 0; s2 < 2; ++s2)
#pragma unroll
                    for (int reg = 0; reg < 4; ++reg)
                        OsU.qk[(s2 * 16 + q * 4 + reg) * 136 + nt * 16 + r] = f2bf(acc[s2][i][reg] * sc);
            }
        }
        __syncthreads();
        u16* Out = outs[m];
#pragma unroll
        for (int it = 0; it < 2; ++it) {
            int c = tid + it * 256;
            int row = c >> 4, col = (c & 15) * 8;
            *(uint4*)(Out + (m0 + row) * H_ + col) = *(const uint4*)&OsU.qk[row * 136 + col];
        }
    }

    // ---- V transposed: OsU.vt[h][s_local], then Vt[b][h][s] global ----
    __syncthreads();
#pragma unroll
    for (int i = 0; i < 6; ++i) {
        int c = w * 6 + i;
        if ((c >> 3) == 2) {
            int nt = c & 7;
#pragma unroll
            for (int s2 = 0; s2 < 2; ++s2)
#pragma unroll
                for (int reg = 0; reg < 4; ++reg)
                    OsU.vt[(nt * 16 + r) * 40 + s2 * 16 + q * 4 + reg] = f2bf(acc[s2][i][reg]);
        }
    }
    __syncthreads();
    {
        const int bb = blockIdx.x >> 7;           // 128 blocks per batch
        const int s0 = (blockIdx.x & 127) * 32;
#pragma unroll
        for (int it = 0; it < 2; ++it) {
            int c = tid + it * 256;
            int h = c >> 2, sh = (c & 3) * 8;
            *(uint4*)(Vto + ((size_t)bb * H_ + h) * S_ + s0 + sh) =
                *(const uint4*)&OsU.vt[h * 40 + sh];
        }
    }
}

// ---------------------------------------------------------------------------
// Kernel 2: causal flash attention, LDS-STAGED K/V (round-9 intent; round-10
// fixes the launch bug: the pair/segment decomposition defines EXACTLY
// 4b x 32p x 2c = 256 blocks, but r9 launched 512 -> blocks with c=2,3
// duplicated segment-1 work and wrote partials into slot (b*32+p)*2+c,
// colliding with pair p+1's slots (racing writers, wrong qt, wrong l).
// Theory unchanged from r8 post-mortem: per CU, 129 wave-chunks serialize
// at ~1450 cy each with ALL counted pipes idle => the shared serializer is
// the VMEM front-end/L1 (direct-from-global fragment gathers spread 64
// lanes over 32 cachelines). Fix: stage K/V tiles DENSE via global_load_lds,
// serve scattered frag reads from the LDS pipe with XOR swizzle
// byte^=((row&7)<<4) applied BOTH sides (linear LDS dest + inverse-swizzled
// global source + swizzled ds_read; rule #21). QT=64, KT=128, 8 waves =
// qs(2) x kh(4), double-buffered 2x(32K+32K)=128KB LDS, one barrier/tile.
// Outer decomposition + combine = r5's verified pair/segment split.
// Per-chunk math = r8's verified in-register softmax, verbatim.
// ---------------------------------------------------------------------------
__global__ __launch_bounds__(512) void attn_pair_kernel(
    const u16* __restrict__ Q, const u16* __restrict__ K, const u16* __restrict__ Vt,
    void* __restrict__ out, float* __restrict__ OP, float* __restrict__ LP,
    const int* __restrict__ dflag)
{
    __shared__ u16 Ks[2][128 * 128];    // [buf][key*128 + h], swizzled rows (32 KB x2)
    __shared__ u16 Vs[2][128 * 128];    // [buf][h*128 + key], swizzled rows (32 KB x2)
    __shared__ float lpS[8][32];

    const int isf = *dflag;
    const int tid = threadIdx.x;
    const int w = tid >> 6, lane = tid & 63;
    const int l31 = lane & 31, hi = lane >> 5;
    const int qs = w >> 2;              // q-subtile (rows 32*qs..+32 of the 64)
    const int kh = w & 3;               // key quarter of the 128-key tile
    const int bid = blockIdx.x;
    const int b = bid & 3;
    const int p = (bid >> 2) & 31;      // pair index: qtA = p, qtB = 63-p
    const int c = bid >> 7;             // segment 0/1 (grid = 256 -> c in {0,1})
    const int nA = (p >> 1) + 1;        // qtA tiles (1..16)
    const int m = 17 - nA;              // qtB tiles handled by segment 0

    const u16* Kg  = K  + (size_t)b * S_ * H_;
    const u16* Vtg = Vt + (size_t)b * H_ * S_;

    for (int seg = 0; seg < 2; ++seg) {
        int qt, jlo, jhi;
        bool direct;
        if (seg == 0) {
            if (c != 0) continue;
            qt = p; jlo = 0; jhi = nA; direct = true;
        } else {
            qt = 63 - p;
            const int nB = ((63 - p) >> 1) + 1;
            jlo = (c == 0) ? 0 : m; jhi = (c == 0) ? m : nB; direct = false;
        }
        const int nT = (qt >> 1) + 1;   // diagonal tile index + 1
        const u16* Qg = Q + ((size_t)b * S_ + (size_t)qt * 64) * H_;

        // Q frags (global, dense-ish rows; loaded once per segment)
        s16x8 qf[8];
#pragma unroll
        for (int sl = 0; sl < 8; ++sl)
            qf[sl] = *(const s16x8*)(Qg + (size_t)(qs * 32 + l31) * H_ + sl * 16 + hi * 8);

        f32x16 accO[4];
#pragma unroll
        for (int hg = 0; hg < 4; ++hg)
#pragma unroll
            for (int i = 0; i < 16; ++i) accO[hg][i] = 0.f;
        float lp = 0.f;

        // ---- stage tile jlo into buffer 0 (dense, inverse-swizzled source) ----
        {
            const int j0 = jlo;
#pragma unroll
            for (int i = 0; i < 4; ++i) {
                int ck = tid + i * 512;                 // 2048 chunks of 16 B
                int row = ck >> 4;                      // 0..127
                int wo = ((ck & 15) * 16) ^ ((row & 7) << 4);   // swizzled byte off
                gl_lds16(Kg + ((size_t)j0 * 128 + row) * H_ + (wo >> 1), &Ks[0][ck * 8]);
                gl_lds16(Vtg + (size_t)row * S_ + j0 * 128 + (wo >> 1), &Vs[0][ck * 8]);
            }
        }

        for (int j = jlo; j < jhi; ++j) {
            const int buf = (j - jlo) & 1;
            __syncthreads();   // drains vmcnt: tile j staged; readers of buf^1 done

            if (j + 1 < jhi) {   // stage next tile into the other buffer
                const int jn = j + 1;
#pragma unroll
                for (int i = 0; i < 4; ++i) {
                    int ck = tid + i * 512;
                    int row = ck >> 4;
                    int wo = ((ck & 15) * 16) ^ ((row & 7) << 4);
                    gl_lds16(Kg + ((size_t)jn * 128 + row) * H_ + (wo >> 1), &Ks[buf ^ 1][ck * 8]);
                    gl_lds16(Vtg + (size_t)row * S_ + jn * 128 + (wo >> 1), &Vs[buf ^ 1][ck * 8]);
                }
            }

            // ---- K frags from LDS (swizzled ds_read_b128) ----
            const int kr = kh * 32 + l31;               // key within tile
            const u16* kbase = &Ks[buf][kr * 128];
            s16x8 kf[8];
#pragma unroll
            for (int sl = 0; sl < 8; ++sl)
                kf[sl] = *(const s16x8*)&kbase[((sl * 32 + hi * 16) ^ ((kr & 7) << 4)) >> 1];

            // ---- S^T = K Q^T : 2 split accumulator chains for ILP ----
            f32x16 s0, s1;
#pragma unroll
            for (int i = 0; i < 16; ++i) { s0[i] = 0.f; s1[i] = 0.f; }
#pragma unroll
            for (int sl = 0; sl < 4; ++sl) {
                s0 = __builtin_amdgcn_mfma_f32_32x32x16_bf16(kf[sl], qf[sl], s0, 0, 0, 0);
                s1 = __builtin_amdgcn_mfma_f32_32x32x16_bf16(kf[sl + 4], qf[sl + 4], s1, 0, 0, 0);
            }

            // ---- V frags from LDS ----
            s16x8 vf[4][2];
#pragma unroll
            for (int hg = 0; hg < 4; ++hg) {
                const int h = hg * 32 + l31;
                const u16* vbase = &Vs[buf][h * 128];
#pragma unroll
                for (int ks = 0; ks < 2; ++ks)
                    vf[hg][ks] = *(const s16x8*)&vbase[((kh * 64 + ks * 32 + hi * 16) ^ ((h & 7) << 4)) >> 1];
            }

            // ---- lane-local softmax (no max-pass; clamp 80), diagonal mask ----
            const bool diag = (j == nT - 1);
            float pv16[16];
#pragma unroll
            for (int r = 0; r < 16; ++r) {
                float s = fminf(s0[r] + s1[r], 80.f);
                float pv = __expf(s);
                int gkey = j * 128 + kh * 32 + ((r & 3) + 8 * (r >> 2) + 4 * hi);
                int grow = qt * 64 + qs * 32 + l31;
                if (diag && gkey > grow) pv = 0.f;
                lp += pv;
                pv16[r] = pv;
            }

            // ---- P -> PV A-frags: 8 cvt_pk + 4 permlane32_swap (T12, r8 verbatim) ----
            u32 w01 = cvtpk_bf16(pv16[0], pv16[1]),  w23 = cvtpk_bf16(pv16[2], pv16[3]);
            u32 w45 = cvtpk_bf16(pv16[4], pv16[5]),  w67 = cvtpk_bf16(pv16[6], pv16[7]);
            pl32swap(w01, w45);
            pl32swap(w23, w67);
            u32 x01 = cvtpk_bf16(pv16[8], pv16[9]),   x23 = cvtpk_bf16(pv16[10], pv16[11]);
            u32 x45 = cvtpk_bf16(pv16[12], pv16[13]), x67 = cvtpk_bf16(pv16[14], pv16[15]);
            pl32swap(x01, x45);
            pl32swap(x23, x67);
            union { u32 u[4]; s16x8 v; } pa0, pa1;
            pa0.u[0] = w01; pa0.u[1] = w23; pa0.u[2] = w45; pa0.u[3] = w67;
            pa1.u[0] = x01; pa1.u[1] = x23; pa1.u[2] = x45; pa1.u[3] = x67;

            // ---- O += P V ----
#pragma unroll
            for (int hg = 0; hg < 4; ++hg) {
                accO[hg] = __builtin_amdgcn_mfma_f32_32x32x16_bf16(pa0.v, vf[hg][0], accO[hg], 0, 0, 0);
                accO[hg] = __builtin_amdgcn_mfma_f32_32x32x16_bf16(pa1.v, vf[hg][1], accO[hg], 0, 0, 0);
            }
        }

        // ---- l: merge hi halves, publish per wave ----
        lp += __shfl_xor(lp, 32);
        if (lane < 32) lpS[w][l31] = lp;
        __syncthreads();   // all compute done; no staging in flight; Ks reusable

        // ---- serialized O combine across kh waves into opSf (reuses Ks[0]) ----
        float* opSf = (float*)&Ks[0][0];    // [64][128] f32 = 32 KB
        for (int s = 0; s < 4; ++s) {
            if (kh == s) {
                float* dst = opSf + qs * 32 * 128;
#pragma unroll
                for (int hg = 0; hg < 4; ++hg)
#pragma unroll
                    for (int r = 0; r < 16; ++r) {
                        int idx = ((r & 3) + 8 * (r >> 2) + 4 * hi) * 128 + hg * 32 + l31;
                        if (s == 0) dst[idx] = accO[hg][r];
                        else        dst[idx] += accO[hg][r];
                    }
            }
            __syncthreads();
        }

        const int row = tid >> 3;            // 0..63
        const int col = (tid & 7) * 16;      // 0..112
        const int rq = row & 31, rs = row >> 5;
        const float lrow = lpS[rs * 4 + 0][rq] + lpS[rs * 4 + 1][rq] +
                           lpS[rs * 4 + 2][rq] + lpS[rs * 4 + 3][rq];
        const float* src = opSf + (rs * 32 + rq) * 128 + col;

        if (direct) {
            const float inv = 1.0f / lrow;
            const size_t orow = (size_t)b * S_ + (size_t)qt * 64 + row;
            if (isf) {
                float* dst = (float*)out + orow * H_ + col;
#pragma unroll
                for (int i = 0; i < 4; ++i) {
                    float4 v = *(const float4*)(src + i * 4);
                    v.x *= inv; v.y *= inv; v.z *= inv; v.w *= inv;
                    *(float4*)(dst + i * 4) = v;
                }
            } else {
                u16* dst = (u16*)out + orow * H_ + col;
#pragma unroll
                for (int hh = 0; hh < 2; ++hh) {
                    union { u16 u[8]; uint4 v; } pk;
#pragma unroll
                    for (int i = 0; i < 8; ++i) pk.u[i] = f2bf(src[hh * 8 + i] * inv);
                    *(uint4*)(dst + hh * 8) = pk.v;
                }
            }
        } else {
            const size_t slot = (size_t)((b * 32 + p) * 2 + c);
            float* Os = OP + slot * 64 * 128;
#pragma unroll
            for (int i = 0; i < 4; ++i)
                *(float4*)(Os + row * 128 + col + i * 4) = *(const float4*)(src + i * 4);
            if (tid < 64)
                LP[slot * 64 + tid] = lpS[(tid >> 5) * 4 + 0][tid & 31] + lpS[(tid >> 5) * 4 + 1][tid & 31] +
                                      lpS[(tid >> 5) * 4 + 2][tid & 31] + lpS[(tid >> 5) * 4 + 3][tid & 31];
        }
        __syncthreads();   // opSf (=Ks[0]) free before next segment's staging
    }
}

// ---------------------------------------------------------------------------
// Kernel 3: combine the key-split long q-tiles (qt64 = 32..63 per batch):
// O = (O0 + O1) / (l0 + l1). Grid 128 = 4b x 32qt, 256 threads. (r5 verified)
// ---------------------------------------------------------------------------
__global__ __launch_bounds__(256) void combine_kernel(
    const float* __restrict__ OP, const float* __restrict__ LP,
    void* __restrict__ out, const int* __restrict__ dflag)
{
    const int isf = *dflag;
    const int bid = blockIdx.x;
    const int b = bid >> 5;
    const int qtl = bid & 31;            // qt64 = 32 + qtl, pair p = 31 - qtl
    const int p = 31 - qtl;
    const size_t s0 = (size_t)((b * 32 + p) * 2);
    const int tid = threadIdx.x;
    const int row = tid >> 2;            // 0..63
    const int col0 = (tid & 3) * 32;     // 0,32,64,96

    const float* O0 = OP + (s0 * 64 + row) * 128 + col0;
    const float* O1 = OP + ((s0 + 1) * 64 + row) * 128 + col0;
    const float l = LP[s0 * 64 + row] + LP[(s0 + 1) * 64 + row];
    const float inv = 1.0f / l;

    float vals[32];
#pragma unroll
    for (int i = 0; i < 8; ++i) {
        float4 a = *(const float4*)(O0 + i * 4);
        float4 bb = *(const float4*)(O1 + i * 4);
        vals[i * 4 + 0] = (a.x + bb.x) * inv;
        vals[i * 4 + 1] = (a.y + bb.y) * inv;
        vals[i * 4 + 2] = (a.z + bb.z) * inv;
        vals[i * 4 + 3] = (a.w + bb.w) * inv;
    }

    const size_t orow = (size_t)b * S_ + (size_t)(32 + qtl) * 64 + row;
    if (isf) {
        float* dst = (float*)out + orow * H_ + col0;
#pragma unroll
        for (int i = 0; i < 8; ++i)
            *(float4*)(dst + i * 4) = *(const float4*)(&vals[i * 4]);
    } else {
        u16* dst = (u16*)out + orow * H_ + col0;
#pragma unroll
        for (int hh = 0; hh < 4; ++hh) {
            union { u16 u[8]; uint4 v; } pk;
#pragma unroll
            for (int i = 0; i < 8; ++i) pk.u[i] = f2bf(vals[hh * 8 + i]);
            *(uint4*)(dst + hh * 8) = pk.v;
        }
    }
}

extern "C" void kernel_launch(void* const* d_in, const int* in_sizes, int n_in,
                              void* d_out, int out_size, void* d_ws, size_t ws_size,
                              hipStream_t stream) {
    (void)in_sizes; (void)n_in; (void)out_size; (void)ws_size;
    const void* X  = d_in[0];
    const void* Wq = d_in[1];
    const void* Wk = d_in[2];
    const void* Wv = d_in[3];

    int* dflag = (int*)d_ws;                          // 256 B header
    u16* Qw = (u16*)((char*)d_ws + 256);
    const size_t n = (size_t)B_ * S_ * H_;            // 2M elems per tensor
    u16* Kw = Qw + n;
    u16* Vtw = Kw + n;                                // V stored transposed [b][h][s]
    u16* Wt = Vtw + n;                                // 3*1024*128 bf16 = 768 KB
    float* OP = (float*)(Wt + 3 * 1024 * 128);        // 256 slots x 64x128 f32 = 8 MB
    float* LP = OP + (size_t)256 * 64 * 128;          // 256 x 64 f32 = 64 KB

    detect_dtype_kernel<<<1, 256, 0, stream>>>((const u32*)Wq, dflag);
    prep_w_kernel<<<dim3(32, 3), 256, 0, stream>>>(Wq, Wk, Wv, Wt, dflag);
    qkv_kernel<<<512, 256, 0, stream>>>(X, Wt, Qw, Kw, Vtw, dflag);
    // Decomposition defines exactly 4b x 32p x 2c = 256 blocks (r9 bug: 512).
    attn_pair_kernel<<<256, 512, 0, stream>>>(Qw, Kw, Vtw, d_out, OP, LP, dflag);
    combine_kernel<<<128, 256, 0, stream>>>(OP, LP, d_out, dflag);
}

// Round 11
// 184.506 us; speedup vs baseline: 1.1848x; 1.0400x over previous
//
#include <hip/hip_runtime.h>
#include <hip/hip_bf16.h>

#define B_ 4
#define S_ 4096
#define D_ 1024
#define H_ 128

typedef unsigned short u16;
typedef unsigned int u32;
typedef short s16x8 __attribute__((ext_vector_type(8)));   // 8 bf16 (4 VGPRs)
typedef float f32x4 __attribute__((ext_vector_type(4)));   // MFMA 16x16 acc
typedef float f32x16 __attribute__((ext_vector_type(16))); // MFMA 32x32 acc

__device__ __forceinline__ u16 f2bf(float f) {
    u32 x = __float_as_uint(f);
    u32 r = x + 0x7fffu + ((x >> 16) & 1u);   // RNE
    return (u16)(r >> 16);
}

// v_cvt_pk_bf16_f32: dst = {bf16(a) lo16, bf16(b) hi16}
__device__ __forceinline__ u32 cvtpk_bf16(float a, float b) {
    u32 r;
    asm("v_cvt_pk_bf16_f32 %0, %1, %2" : "=v"(r) : "v"(a), "v"(b));
    return r;
}
// v_permlane32_swap_b32: exchanges x.hi-lanes <-> y.lo-lanes (both updated)
__device__ __forceinline__ void pl32swap(u32& x, u32& y) {
    asm("v_permlane32_swap_b32 %0, %1" : "+v"(x), "+v"(y));
}

// async global->LDS, 16 B per lane (m97 pattern; zero staging VGPRs).
// LDS dest must be wave-uniform base + lane*16 (m104) -- callers ensure.
__device__ __forceinline__ void gl_lds16(const u16* g, u16* l) {
    __builtin_amdgcn_global_load_lds(
        (const __attribute__((address_space(1))) u32*)g,
        (__attribute__((address_space(3))) u32*)l, 16, 0, 0);
}

// ---------------------------------------------------------------------------
// Kernel 0: input dtype detection (fp32 vs bf16). Verified in round 3.
// ---------------------------------------------------------------------------
__global__ void detect_dtype_kernel(const u32* __restrict__ w, int* __restrict__ flag) {
    __shared__ int smax[256];
    const int tid = threadIdx.x;
    int m = 0;
    for (int i = tid; i < 1024; i += 256) {
        u32 x = w[i];
        m = max(m, max((int)((x >> 7) & 0xFF), (int)((x >> 23) & 0xFF)));
    }
    smax[tid] = m;
    __syncthreads();
    if (tid == 0) {
        int mm = 0;
        for (int i = 0; i < 256; ++i) mm = max(mm, smax[i]);
        *flag = (mm >= 200) ? 1 : 0;
    }
}

// ---------------------------------------------------------------------------
// Kernel 0b: W -> Wt, bf16, transposed + tiled so a B-fragment is 16 B
// contiguous: Wt[((mat*32+kt)*128 + n)*32 + k]. Tile (mat,kt) = 8 KB.
// ---------------------------------------------------------------------------
__global__ __launch_bounds__(256) void prep_w_kernel(
    const void* __restrict__ Wq, const void* __restrict__ Wk, const void* __restrict__ Wv,
    u16* __restrict__ Wt, const int* __restrict__ dflag)
{
    const int kt = blockIdx.x, mat = blockIdx.y;
    const void* W = (mat == 0) ? Wq : (mat == 1) ? Wk : Wv;
    const int isf = *dflag;
    const int t = threadIdx.x;
    const int kk = t >> 3;            // 0..31 (k within tile)
    const int n0 = (t & 7) * 16;      // 16 n per thread
    u16 vals[16];
    if (isf) {
        const float* wp = (const float*)W + (size_t)(kt * 32 + kk) * H_ + n0;
#pragma unroll
        for (int i = 0; i < 16; ++i) vals[i] = f2bf(wp[i]);
    } else {
        const u16* wp = (const u16*)W + (size_t)(kt * 32 + kk) * H_ + n0;
#pragma unroll
        for (int i = 0; i < 16; ++i) vals[i] = wp[i];
    }
    const size_t base = (size_t)(mat * 32 + kt) * 128;
#pragma unroll
    for (int i = 0; i < 16; ++i)
        Wt[(base + n0 + i) * 32 + kk] = vals[i];
}

// ---------------------------------------------------------------------------
// Kernel 1: fused QKV GEMM v5. Round-10 post-mortem: qkv is now the
// bottleneck (64us) with the SAME line-fill signature attention had:
// 2400 cy per block-kt == 640 L1 lines (W stage 384 dense + A gathers 256
// scattered, 4x WAVE-REDUNDANT: all 4 waves read identical A rows).
// Fix, same medicine as r10-attn: (1) stage A densely via global_load_lds
// ONCE per block, XOR-swizzled both sides (linear LDS dest,
// inverse-swizzled per-lane global source, swizzled LDS read); (2) BM=64,
// 512 threads, grid 256 (1 block/CU) to halve W-staging lines per output
// row. Per-CU lines drop 41k -> 16.4k (2.5x). Per-wave MFMA code identical
// (wave = (ws,wc): rows ws*32, frags wc*6..+6; 12 MFMA/kt). Epilogue
// bounces through the dead Ws buffer ([64][136] qk / [128][72] vt).
// ---------------------------------------------------------------------------
__global__ __launch_bounds__(512) void qkv_kernel(
    const void* __restrict__ Xv, const u16* __restrict__ Wt,
    u16* __restrict__ Qo, u16* __restrict__ Ko, u16* __restrict__ Vto,
    const int* __restrict__ dflag)
{
    __shared__ u16 Ws[2][384 * 32];       // 2 x 24 KB W tiles
    __shared__ float Asf[2][64 * 32];     // 2 x 8 KB A tiles (f32; bf16 aliases low half)

    const int isf = *dflag;
    const int tid = threadIdx.x;
    const int w = tid >> 6, lane = tid & 63;
    const int ws = w >> 2, wc = w & 3;    // row-half, frag-quarter
    const int r = lane & 15, q = lane >> 4;
    const size_t m0 = (size_t)blockIdx.x * 64;

    const float* Xf = (const float*)Xv;
    const u16*   Xb = (const u16*)Xv;

    f32x4 acc[2][6];   // [row strip within ws][frag]
#pragma unroll
    for (int s2 = 0; s2 < 2; ++s2)
#pragma unroll
        for (int i = 0; i < 6; ++i) acc[s2][i] = (f32x4){0.f, 0.f, 0.f, 0.f};

    // ---- stage W tile kt=0 (1536 chunks, 3/thread) ----
#pragma unroll
    for (int i = 0; i < 3; ++i) {
        int c = tid + i * 512;
        gl_lds16(Wt + (size_t)((c >> 9) * 32) * 4096 + (c & 511) * 8, &Ws[0][c * 8]);
    }
    // ---- stage A tile kt=0 (dense, inverse-swizzled source) ----
    if (isf) {
        int ck = tid;                          // 512 chunks of 16 B (8 KB)
        int row = ck >> 3, co = (ck & 7) ^ (row & 7);
        gl_lds16((const u16*)(Xf + (m0 + row) * D_ + co * 4), (u16*)&Asf[0][ck * 4]);
    } else if (tid < 256) {
        int ck = tid;                          // 256 chunks of 16 B (4 KB)
        int row = ck >> 2, co = (ck & 3) ^ (row & 3);
        gl_lds16(Xb + (m0 + row) * D_ + co * 8, (u16*)&Asf[0][0] + ck * 8);
    }

    for (int kt = 0; kt < 32; ++kt) {
        const int buf = kt & 1;
        __syncthreads();   // drains vmcnt: Ws/As[buf] ready; readers of buf^1 done

        if (kt + 1 < 32) {   // stage next tiles into the other buffer
#pragma unroll
            for (int i = 0; i < 3; ++i) {
                int c = tid + i * 512;
                gl_lds16(Wt + (size_t)((c >> 9) * 32 + kt + 1) * 4096 + (c & 511) * 8,
                         &Ws[buf ^ 1][c * 8]);
            }
            const int k0 = (kt + 1) * 32;
            if (isf) {
                int ck = tid;
                int row = ck >> 3, co = (ck & 7) ^ (row & 7);
                gl_lds16((const u16*)(Xf + (m0 + row) * D_ + k0 + co * 4),
                         (u16*)&Asf[buf ^ 1][ck * 4]);
            } else if (tid < 256) {
                int ck = tid;
                int row = ck >> 2, co = (ck & 3) ^ (row & 3);
                gl_lds16(Xb + (m0 + row) * D_ + k0 + co * 8,
                         (u16*)&Asf[buf ^ 1][0] + ck * 8);
            }
        }

        // ---- A frags from LDS (swizzled), convert to bf16 ----
        s16x8 a[2];
        if (isf) {
#pragma unroll
            for (int s2 = 0; s2 < 2; ++s2) {
                const int row = ws * 32 + s2 * 16 + r;
                const int sw = row & 7;
                const float* ap = &Asf[buf][row * 32];
                float4 fa = *(const float4*)&ap[((2 * q) ^ sw) * 4];
                float4 fb = *(const float4*)&ap[((2 * q + 1) ^ sw) * 4];
                union { u16 u[8]; s16x8 v; } pk;
                pk.u[0] = f2bf(fa.x); pk.u[1] = f2bf(fa.y);
                pk.u[2] = f2bf(fa.z); pk.u[3] = f2bf(fa.w);
                pk.u[4] = f2bf(fb.x); pk.u[5] = f2bf(fb.y);
                pk.u[6] = f2bf(fb.z); pk.u[7] = f2bf(fb.w);
                a[s2] = pk.v;
            }
        } else {
            const u16* ab = (const u16*)&Asf[buf][0];
#pragma unroll
            for (int s2 = 0; s2 < 2; ++s2) {
                const int row = ws * 32 + s2 * 16 + r;
                a[s2] = *(const s16x8*)&ab[row * 32 + ((q ^ (row & 3)) * 8)];
            }
        }

#pragma unroll
        for (int i = 0; i < 6; ++i) {
            int c = wc * 6 + i;   // mat = c>>3, nt = c&7
            s16x8 b = *(const s16x8*)&Ws[buf][(c >> 3) * 4096 + ((c & 7) * 16 + r) * 32 + q * 8];
            acc[0][i] = __builtin_amdgcn_mfma_f32_16x16x32_bf16(a[0], b, acc[0][i], 0, 0, 0);
            acc[1][i] = __builtin_amdgcn_mfma_f32_16x16x32_bf16(a[1], b, acc[1][i], 0, 0, 0);
        }
    }

    // ---- epilogue: Q and K row-major via LDS bounce (reuses dead Ws) ----
    u16* outs[2] = {Qo, Ko};
    u16* qk = &Ws[0][0];                     // [64][136] u16 = 17.4 KB
    for (int m = 0; m < 2; ++m) {
        const float sc = (m == 0) ? 0.08838834764831845f : 1.0f;
        __syncthreads();
#pragma unroll
        for (int i = 0; i < 6; ++i) {
            int c = wc * 6 + i;
            if ((c >> 3) == m) {
                int nt = c & 7;
#pragma unroll
                for (int s2 = 0; s2 < 2; ++s2)
#pragma unroll
                    for (int reg = 0; reg < 4; ++reg)
                        qk[(ws * 32 + s2 * 16 + q * 4 + reg) * 136 + nt * 16 + r] =
                            f2bf(acc[s2][i][reg] * sc);
            }
        }
        __syncthreads();
        u16* Out = outs[m];
#pragma unroll
        for (int it = 0; it < 2; ++it) {
            int c2 = tid + it * 512;         // 1024 chunks: 64 rows x 16
            int row = c2 >> 4, col = (c2 & 15) * 8;
            *(uint4*)(Out + (m0 + row) * H_ + col) = *(const uint4*)&qk[row * 136 + col];
        }
    }

    // ---- V transposed: vt[h][s_local] (reuses Ws), then Vt[b][h][s] ----
    __syncthreads();
    u16* vt = &Ws[0][0];                     // [128][72] u16 = 18.4 KB
#pragma unroll
    for (int i = 0; i < 6; ++i) {
        int c = wc * 6 + i;
        if ((c >> 3) == 2) {
            int nt = c & 7;
#pragma unroll
            for (int s2 = 0; s2 < 2; ++s2)
#pragma unroll
                for (int reg = 0; reg < 4; ++reg)
                    vt[(nt * 16 + r) * 72 + ws * 32 + s2 * 16 + q * 4 + reg] =
                        f2bf(acc[s2][i][reg]);
        }
    }
    __syncthreads();
    {
        const int bb = blockIdx.x >> 6;      // 64 blocks per batch
        const int s0 = (blockIdx.x & 63) * 64;
#pragma unroll
        for (int it = 0; it < 2; ++it) {
            int c2 = tid + it * 512;         // 1024 chunks: 128 h x 8
            int h = c2 >> 3, sh = (c2 & 7) * 8;
            *(uint4*)(Vto + ((size_t)bb * H_ + h) * S_ + s0 + sh) =
                *(const uint4*)&vt[h * 72 + sh];
        }
    }
}

// ---------------------------------------------------------------------------
// Kernel 2: causal flash attention, LDS-STAGED K/V (r10, passing).
// Dense global_load_lds staging + XOR-swizzled LDS reads (both-sides);
// QT=64, KT=128, 8 waves = qs(2) x kh(4), double-buffered 128KB LDS,
// one barrier/tile; r8's in-register softmax verbatim; r5's pair/segment
// decomposition (EXACTLY 256 blocks) + combine.
// ---------------------------------------------------------------------------
__global__ __launch_bounds__(512) void attn_pair_kernel(
    const u16* __restrict__ Q, const u16* __restrict__ K, const u16* __restrict__ Vt,
    void* __restrict__ out, float* __restrict__ OP, float* __restrict__ LP,
    const int* __restrict__ dflag)
{
    __shared__ u16 Ks[2][128 * 128];    // [buf][key*128 + h], swizzled rows (32 KB x2)
    __shared__ u16 Vs[2][128 * 128];    // [buf][h*128 + key], swizzled rows (32 KB x2)
    __shared__ float lpS[8][32];

    const int isf = *dflag;
    const int tid = threadIdx.x;
    const int w = tid >> 6, lane = tid & 63;
    const int l31 = lane & 31, hi = lane >> 5;
    const int qs = w >> 2;              // q-subtile (rows 32*qs..+32 of the 64)
    const int kh = w & 3;               // key quarter of the 128-key tile
    const int bid = blockIdx.x;
    const int b = bid & 3;
    const int p = (bid >> 2) & 31;      // pair index: qtA = p, qtB = 63-p
    const int c = bid >> 7;             // segment 0/1 (grid = 256 -> c in {0,1})
    const int nA = (p >> 1) + 1;        // qtA tiles (1..16)
    const int m = 17 - nA;              // qtB tiles handled by segment 0

    const u16* Kg  = K  + (size_t)b * S_ * H_;
    const u16* Vtg = Vt + (size_t)b * H_ * S_;

    for (int seg = 0; seg < 2; ++seg) {
        int qt, jlo, jhi;
        bool direct;
        if (seg == 0) {
            if (c != 0) continue;
            qt = p; jlo = 0; jhi = nA; direct = true;
        } else {
            qt = 63 - p;
            const int nB = ((63 - p) >> 1) + 1;
            jlo = (c == 0) ? 0 : m; jhi = (c == 0) ? m : nB; direct = false;
        }
        const int nT = (qt >> 1) + 1;   // diagonal tile index + 1
        const u16* Qg = Q + ((size_t)b * S_ + (size_t)qt * 64) * H_;

        // Q frags (global, dense-ish rows; loaded once per segment)
        s16x8 qf[8];
#pragma unroll
        for (int sl = 0; sl < 8; ++sl)
            qf[sl] = *(const s16x8*)(Qg + (size_t)(qs * 32 + l31) * H_ + sl * 16 + hi * 8);

        f32x16 accO[4];
#pragma unroll
        for (int hg = 0; hg < 4; ++hg)
#pragma unroll
            for (int i = 0; i < 16; ++i) accO[hg][i] = 0.f;
        float lp = 0.f;

        // ---- stage tile jlo into buffer 0 (dense, inverse-swizzled source) ----
        {
            const int j0 = jlo;
#pragma unroll
            for (int i = 0; i < 4; ++i) {
                int ck = tid + i * 512;                 // 2048 chunks of 16 B
                int row = ck >> 4;                      // 0..127
                int wo = ((ck & 15) * 16) ^ ((row & 7) << 4);   // swizzled byte off
                gl_lds16(Kg + ((size_t)j0 * 128 + row) * H_ + (wo >> 1), &Ks[0][ck * 8]);
                gl_lds16(Vtg + (size_t)row * S_ + j0 * 128 + (wo >> 1), &Vs[0][ck * 8]);
            }
        }

        for (int j = jlo; j < jhi; ++j) {
            const int buf = (j - jlo) & 1;
            __syncthreads();   // drains vmcnt: tile j staged; readers of buf^1 done

            if (j + 1 < jhi) {   // stage next tile into the other buffer
                const int jn = j + 1;
#pragma unroll
                for (int i = 0; i < 4; ++i) {
                    int ck = tid + i * 512;
                    int row = ck >> 4;
                    int wo = ((ck & 15) * 16) ^ ((row & 7) << 4);
                    gl_lds16(Kg + ((size_t)jn * 128 + row) * H_ + (wo >> 1), &Ks[buf ^ 1][ck * 8]);
                    gl_lds16(Vtg + (size_t)row * S_ + jn * 128 + (wo >> 1), &Vs[buf ^ 1][ck * 8]);
                }
            }

            // ---- K frags from LDS (swizzled ds_read_b128) ----
            const int kr = kh * 32 + l31;               // key within tile
            const u16* kbase = &Ks[buf][kr * 128];
            s16x8 kf[8];
#pragma unroll
            for (int sl = 0; sl < 8; ++sl)
                kf[sl] = *(const s16x8*)&kbase[((sl * 32 + hi * 16) ^ ((kr & 7) << 4)) >> 1];

            // ---- S^T = K Q^T : 2 split accumulator chains for ILP ----
            f32x16 s0, s1;
#pragma unroll
            for (int i = 0; i < 16; ++i) { s0[i] = 0.f; s1[i] = 0.f; }
#pragma unroll
            for (int sl = 0; sl < 4; ++sl) {
                s0 = __builtin_amdgcn_mfma_f32_32x32x16_bf16(kf[sl], qf[sl], s0, 0, 0, 0);
                s1 = __builtin_amdgcn_mfma_f32_32x32x16_bf16(kf[sl + 4], qf[sl + 4], s1, 0, 0, 0);
            }

            // ---- V frags from LDS ----
            s16x8 vf[4][2];
#pragma unroll
            for (int hg = 0; hg < 4; ++hg) {
                const int h = hg * 32 + l31;
                const u16* vbase = &Vs[buf][h * 128];
#pragma unroll
                for (int ks = 0; ks < 2; ++ks)
                    vf[hg][ks] = *(const s16x8*)&vbase[((kh * 64 + ks * 32 + hi * 16) ^ ((h & 7) << 4)) >> 1];
            }

            // ---- lane-local softmax (no max-pass; clamp 80), diagonal mask ----
            const bool diag = (j == nT - 1);
            float pv16[16];
#pragma unroll
            for (int r = 0; r < 16; ++r) {
                float s = fminf(s0[r] + s1[r], 80.f);
                float pv = __expf(s);
                int gkey = j * 128 + kh * 32 + ((r & 3) + 8 * (r >> 2) + 4 * hi);
                int grow = qt * 64 + qs * 32 + l31;
                if (diag && gkey > grow) pv = 0.f;
                lp += pv;
                pv16[r] = pv;
            }

            // ---- P -> PV A-frags: 8 cvt_pk + 4 permlane32_swap (T12, r8 verbatim) ----
            u32 w01 = cvtpk_bf16(pv16[0], pv16[1]),  w23 = cvtpk_bf16(pv16[2], pv16[3]);
            u32 w45 = cvtpk_bf16(pv16[4], pv16[5]),  w67 = cvtpk_bf16(pv16[6], pv16[7]);
            pl32swap(w01, w45);
            pl32swap(w23, w67);
            u32 x01 = cvtpk_bf16(pv16[8], pv16[9]),   x23 = cvtpk_bf16(pv16[10], pv16[11]);
            u32 x45 = cvtpk_bf16(pv16[12], pv16[13]), x67 = cvtpk_bf16(pv16[14], pv16[15]);
            pl32swap(x01, x45);
            pl32swap(x23, x67);
            union { u32 u[4]; s16x8 v; } pa0, pa1;
            pa0.u[0] = w01; pa0.u[1] = w23; pa0.u[2] = w45; pa0.u[3] = w67;
            pa1.u[0] = x01; pa1.u[1] = x23; pa1.u[2] = x45; pa1.u[3] = x67;

            // ---- O += P V ----
#pragma unroll
            for (int hg = 0; hg < 4; ++hg) {
                accO[hg] = __builtin_amdgcn_mfma_f32_32x32x16_bf16(pa0.v, vf[hg][0], accO[hg], 0, 0, 0);
                accO[hg] = __builtin_amdgcn_mfma_f32_32x32x16_bf16(pa1.v, vf[hg][1], accO[hg], 0, 0, 0);
            }
        }

        // ---- l: merge hi halves, publish per wave ----
        lp += __shfl_xor(lp, 32);
        if (lane < 32) lpS[w][l31] = lp;
        __syncthreads();   // all compute done; no staging in flight; Ks reusable

        // ---- serialized O combine across kh waves into opSf (reuses Ks[0]) ----
        float* opSf = (float*)&Ks[0][0];    // [64][128] f32 = 32 KB
        for (int s = 0; s < 4; ++s) {
            if (kh == s) {
                float* dst = opSf + qs * 32 * 128;
#pragma unroll
                for (int hg = 0; hg < 4; ++hg)
#pragma unroll
                    for (int r = 0; r < 16; ++r) {
                        int idx = ((r & 3) + 8 * (r >> 2) + 4 * hi) * 128 + hg * 32 + l31;
                        if (s == 0) dst[idx] = accO[hg][r];
                        else        dst[idx] += accO[hg][r];
                    }
            }
            __syncthreads();
        }

        const int row = tid >> 3;            // 0..63
        const int col = (tid & 7) * 16;      // 0..112
        const int rq = row & 31, rs = row >> 5;
        const float lrow = lpS[rs * 4 + 0][rq] + lpS[rs * 4 + 1][rq] +
                           lpS[rs * 4 + 2][rq] + lpS[rs * 4 + 3][rq];
        const float* src = opSf + (rs * 32 + rq) * 128 + col;

        if (direct) {
            const float inv = 1.0f / lrow;
            const size_t orow = (size_t)b * S_ + (size_t)qt * 64 + row;
            if (isf) {
                float* dst = (float*)out + orow * H_ + col;
#pragma unroll
                for (int i = 0; i < 4; ++i) {
                    float4 v = *(const float4*)(src + i * 4);
                    v.x *= inv; v.y *= inv; v.z *= inv; v.w *= inv;
                    *(float4*)(dst + i * 4) = v;
                }
            } else {
                u16* dst = (u16*)out + orow * H_ + col;
#pragma unroll
                for (int hh = 0; hh < 2; ++hh) {
                    union { u16 u[8]; uint4 v; } pk;
#pragma unroll
                    for (int i = 0; i < 8; ++i) pk.u[i] = f2bf(src[hh * 8 + i] * inv);
                    *(uint4*)(dst + hh * 8) = pk.v;
                }
            }
        } else {
            const size_t slot = (size_t)((b * 32 + p) * 2 + c);
            float* Os = OP + slot * 64 * 128;
#pragma unroll
            for (int i = 0; i < 4; ++i)
                *(float4*)(Os + row * 128 + col + i * 4) = *(const float4*)(src + i * 4);
            if (tid < 64)
                LP[slot * 64 + tid] = lpS[(tid >> 5) * 4 + 0][tid & 31] + lpS[(tid >> 5) * 4 + 1][tid & 31] +
                                      lpS[(tid >> 5) * 4 + 2][tid & 31] + lpS[(tid >> 5) * 4 + 3][tid & 31];
        }
        __syncthreads();   // opSf (=Ks[0]) free before next segment's staging
    }
}

// ---------------------------------------------------------------------------
// Kernel 3: combine the key-split long q-tiles (qt64 = 32..63 per batch):
// O = (O0 + O1) / (l0 + l1). Grid 128 = 4b x 32qt, 256 threads. (r5 verified)
// ---------------------------------------------------------------------------
__global__ __launch_bounds__(256) void combine_kernel(
    const float* __restrict__ OP, const float* __restrict__ LP,
    void* __restrict__ out, const int* __restrict__ dflag)
{
    const int isf = *dflag;
    const int bid = blockIdx.x;
    const int b = bid >> 5;
    const int qtl = bid & 31;            // qt64 = 32 + qtl, pair p = 31 - qtl
    const int p = 31 - qtl;
    const size_t s0 = (size_t)((b * 32 + p) * 2);
    const int tid = threadIdx.x;
    const int row = tid >> 2;            // 0..63
    const int col0 = (tid & 3) * 32;     // 0,32,64,96

    const float* O0 = OP + (s0 * 64 + row) * 128 + col0;
    const float* O1 = OP + ((s0 + 1) * 64 + row) * 128 + col0;
    const float l = LP[s0 * 64 + row] + LP[(s0 + 1) * 64 + row];
    const float inv = 1.0f / l;

    float vals[32];
#pragma unroll
    for (int i = 0; i < 8; ++i) {
        float4 a = *(const float4*)(O0 + i * 4);
        float4 bb = *(const float4*)(O1 + i * 4);
        vals[i * 4 + 0] = (a.x + bb.x) * inv;
        vals[i * 4 + 1] = (a.y + bb.y) * inv;
        vals[i * 4 + 2] = (a.z + bb.z) * inv;
        vals[i * 4 + 3] = (a.w + bb.w) * inv;
    }

    const size_t orow = (size_t)b * S_ + (size_t)(32 + qtl) * 64 + row;
    if (isf) {
        float* dst = (float*)out + orow * H_ + col0;
#pragma unroll
        for (int i = 0; i < 8; ++i)
            *(float4*)(dst + i * 4) = *(const float4*)(&vals[i * 4]);
    } else {
        u16* dst = (u16*)out + orow * H_ + col0;
#pragma unroll
        for (int hh = 0; hh < 4; ++hh) {
            union { u16 u[8]; uint4 v; } pk;
#pragma unroll
            for (int i = 0; i < 8; ++i) pk.u[i] = f2bf(vals[hh * 8 + i]);
            *(uint4*)(dst + hh * 8) = pk.v;
        }
    }
}

extern "C" void kernel_launch(void* const* d_in, const int* in_sizes, int n_in,
                              void* d_out, int out_size, void* d_ws, size_t ws_size,
                              hipStream_t stream) {
    (void)in_sizes; (void)n_in; (void)out_size; (void)ws_size;
    const void* X  = d_in[0];
    const void* Wq = d_in[1];
    const void* Wk = d_in[2];
    const void* Wv = d_in[3];

    int* dflag = (int*)d_ws;                          // 256 B header
    u16* Qw = (u16*)((char*)d_ws + 256);
    const size_t n = (size_t)B_ * S_ * H_;            // 2M elems per tensor
    u16* Kw = Qw + n;
    u16* Vtw = Kw + n;                                // V stored transposed [b][h][s]
    u16* Wt = Vtw + n;                                // 3*1024*128 bf16 = 768 KB
    float* OP = (float*)(Wt + 3 * 1024 * 128);        // 256 slots x 64x128 f32 = 8 MB
    float* LP = OP + (size_t)256 * 64 * 128;          // 256 x 64 f32 = 64 KB

    detect_dtype_kernel<<<1, 256, 0, stream>>>((const u32*)Wq, dflag);
    prep_w_kernel<<<dim3(32, 3), 256, 0, stream>>>(Wq, Wk, Wv, Wt, dflag);
    qkv_kernel<<<256, 512, 0, stream>>>(X, Wt, Qw, Kw, Vtw, dflag);
    attn_pair_kernel<<<256, 512, 0, stream>>>(Qw, Kw, Vtw, d_out, OP, LP, dflag);
    combine_kernel<<<128, 256, 0, stream>>>(OP, LP, d_out, dflag);
}